// Round 1
// 743.888 us; speedup vs baseline: 1.0032x; 1.0032x over previous
//
#include <hip/hip_runtime.h>
#include <math.h>

#define BATCH 8192
#define M 200
#define E 64
#define H1 96    // ADIM/2
#define F1 128   // FEA/2
#define F2 85    // FEA/3
#define F3 64    // FEA/4
#define SH 72    // WbT row stride in halfs
#define MT 13    // ceil(200/16) m-tiles

typedef _Float16 half8_t __attribute__((ext_vector_type(8)));
typedef float floatx4 __attribute__((ext_vector_type(4)));

// One block per batch row b.
//  A) fold WbT = (aW1a + diag(tgt)aW1b)^T (fp16), be = ab1 + tgt@aW1c
//     -- hist tile 0 + other row prefetched at kernel entry so their HBM
//        latency hides under the target load + fold work
//  B) per wave: hoist 12 B-frags + be/w2; loop over m-tiles with rolling
//     2-deep register prefetch of the next tile's hist rows; MFMA ->
//     relu(+be)@aW2 -> aij (butterfly + broadcast), accumulate tmp[k]
//  C) in-quad butterfly of tk, per-wave partials to LDS scratch, reduce
//  D) fused MLP head 256->128->85->64->sigmoid, float4 weight loads +
//     split accumulator chains (no fast-math: manual reassociation)
__global__ __launch_bounds__(256, 4) void din_kernel(
    const float* __restrict__ hist, const float* __restrict__ target,
    const float* __restrict__ other,
    const float* __restrict__ aW1, const float* __restrict__ ab1,
    const float* __restrict__ aW2, const float* __restrict__ ab2,
    const float* __restrict__ oW1, const float* __restrict__ ob1,
    const float* __restrict__ oW2, const float* __restrict__ ob2,
    const float* __restrict__ oW3, const float* __restrict__ ob3,
    const float* __restrict__ fW,  const float* __restrict__ fb,
    float* __restrict__ out)
{
    __shared__ _Float16 WbT[H1 * SH];      // 13824 B
    __shared__ float tgtS[E];
    __shared__ float beS[H1];
    __shared__ float aW2S[H1];
    __shared__ float xS[256];
    __shared__ float scr[512];             // partS / h1 partials / h2p / h3p
    __shared__ float h1S[F1];
    __shared__ float h2S[F2];
    __shared__ float ab2S;

    const int t = threadIdx.x;
    const int b = blockIdx.x;
    const int lane = t & 63;
    const int wv   = t >> 6;
    const int quad = lane >> 4;
    const int lm   = lane & 15;

    // ---- early prefetches: issue before anything else ------------------
    // first hist tile for this wave (mt = wv, always < MT)
    {
    }
    int mt = wv;
    const int row0  = mt * 16 + lm;
    const int rowc0 = row0 < M ? row0 : (M - 1);
    const float4* p0 = (const float4*)(hist + ((size_t)b * M + rowc0) * E + quad * 8);
    float4 f0 = p0[0], g0 = p0[1], f1 = p0[8], g1 = p0[9];
    float oth = 0.f;
    if (t >= 128) oth = other[(size_t)b * 128 + (t - 128)];

    if (t < E) tgtS[t] = target[(size_t)b * E + t];
    if (t == 0) ab2S = ab2[0];
    __syncthreads();

    // ---- Phase A: weight folds ----------------------------------------
    for (int idx = t; idx < E * H1; idx += 256) {
        int k = idx / H1, j = idx - k * H1;
        float w = aW1[idx] + tgtS[k] * aW1[E * H1 + idx];
        WbT[j * SH + k] = (_Float16)w;
    }
    if (t < H1) {
        float s0 = ab1[t], s1 = 0.f, s2 = 0.f, s3 = 0.f;
        const float* wp = aW1 + (size_t)(2 * E) * H1 + t;
        #pragma unroll 4
        for (int k = 0; k < E; k += 4) {
            s0 += tgtS[k]     * wp[(size_t)k * H1];
            s1 += tgtS[k + 1] * wp[(size_t)(k + 1) * H1];
            s2 += tgtS[k + 2] * wp[(size_t)(k + 2) * H1];
            s3 += tgtS[k + 3] * wp[(size_t)(k + 3) * H1];
        }
        beS[t] = (s0 + s1) + (s2 + s3);
        aW2S[t] = aW2[t];
    }
    __syncthreads();

    // ---- Phase B: MFMA + fused aij + in-register tmp accumulation -----
    // B[k=kk*32+quad*8+j][n=nt*16+lm]
    half8_t bf[12];
    #pragma unroll
    for (int nt = 0; nt < 6; ++nt) {
        #pragma unroll
        for (int kk = 0; kk < 2; ++kk)
            bf[nt * 2 + kk] =
                *(const half8_t*)&WbT[(nt * 16 + lm) * SH + kk * 32 + quad * 8];
    }
    float beR[6], w2R[6];
    #pragma unroll
    for (int nt = 0; nt < 6; ++nt) {
        beR[nt] = beS[nt * 16 + lm];
        w2R[nt] = aW2S[nt * 16 + lm];
    }

    float tk0[8], tk1[8];
    #pragma unroll
    for (int j = 0; j < 8; ++j) { tk0[j] = 0.f; tk1[j] = 0.f; }

    const int qs16 = (lm >> 2) << 4;
    const int rsel = lm & 3;

    for (; mt < MT; mt += 4) {
        // rolling prefetch of the next tile (wave-uniform branch)
        const int nmt = mt + 4;
        float4 nf0 = f0, ng0 = g0, nf1 = f1, ng1 = g1;
        if (nmt < MT) {
            const int nrow  = nmt * 16 + lm;
            const int nrowc = nrow < M ? nrow : (M - 1);
            const float4* np = (const float4*)(hist + ((size_t)b * M + nrowc) * E + quad * 8);
            nf0 = np[0]; ng0 = np[1]; nf1 = np[8]; ng1 = np[9];
        }

        const int m0  = mt * 16;
        const int row = m0 + lm;
        half8_t a0 = { (_Float16)f0.x, (_Float16)f0.y, (_Float16)f0.z, (_Float16)f0.w,
                       (_Float16)g0.x, (_Float16)g0.y, (_Float16)g0.z, (_Float16)g0.w };
        half8_t a1 = { (_Float16)f1.x, (_Float16)f1.y, (_Float16)f1.z, (_Float16)f1.w,
                       (_Float16)g1.x, (_Float16)g1.y, (_Float16)g1.z, (_Float16)g1.w };

        float s0 = 0.f, s1 = 0.f, s2 = 0.f, s3 = 0.f;
        #pragma unroll
        for (int nt = 0; nt < 6; ++nt) {
            floatx4 acc = {0.f, 0.f, 0.f, 0.f};
            acc = __builtin_amdgcn_mfma_f32_16x16x32_f16(a0, bf[nt * 2],     acc, 0, 0, 0);
            acc = __builtin_amdgcn_mfma_f32_16x16x32_f16(a1, bf[nt * 2 + 1], acc, 0, 0, 0);
            float be_n = beR[nt];
            float w2   = w2R[nt];
            s0 += fmaxf(acc[0] + be_n, 0.f) * w2;
            s1 += fmaxf(acc[1] + be_n, 0.f) * w2;
            s2 += fmaxf(acc[2] + be_n, 0.f) * w2;
            s3 += fmaxf(acc[3] + be_n, 0.f) * w2;
        }
        // sum over the 16 cols handled by this quad (rows m0+quad*4+r)
        #pragma unroll
        for (int off = 1; off < 16; off <<= 1) {
            s0 += __shfl_xor(s0, off);
            s1 += __shfl_xor(s1, off);
            s2 += __shfl_xor(s2, off);
            s3 += __shfl_xor(s3, off);
        }
        // broadcast: lane needs aij[row=m0+lm] = quad(lm>>2)'s s_{lm&3}
        float v0 = __shfl(s0, qs16), v1 = __shfl(s1, qs16);
        float v2 = __shfl(s2, qs16), v3 = __shfl(s3, qs16);
        float aij = (rsel == 0) ? v0 : (rsel == 1) ? v1 : (rsel == 2) ? v2 : v3;
        aij += ab2S;
        aij = (row < M) ? aij : 0.f;

        // tmp[k] += aij * H[row][k]  (k = quad*8+j and 32+quad*8+j)
        tk0[0] += f0.x * aij; tk0[1] += f0.y * aij;
        tk0[2] += f0.z * aij; tk0[3] += f0.w * aij;
        tk0[4] += g0.x * aij; tk0[5] += g0.y * aij;
        tk0[6] += g0.z * aij; tk0[7] += g0.w * aij;
        tk1[0] += f1.x * aij; tk1[1] += f1.y * aij;
        tk1[2] += f1.z * aij; tk1[3] += f1.w * aij;
        tk1[4] += g1.x * aij; tk1[5] += g1.y * aij;
        tk1[6] += g1.z * aij; tk1[7] += g1.w * aij;

        f0 = nf0; g0 = ng0; f1 = nf1; g1 = ng1;
    }

    // ---- Phase C: reduce tk over quad lanes, write per-wave partials --
    #pragma unroll
    for (int j = 0; j < 8; ++j) {
        #pragma unroll
        for (int off = 1; off < 16; off <<= 1) {
            tk0[j] += __shfl_xor(tk0[j], off);
            tk1[j] += __shfl_xor(tk1[j], off);
        }
    }
    if (lm == 0) {
        #pragma unroll
        for (int j = 0; j < 8; ++j) {
            scr[wv * E + quad * 8 + j]      = tk0[j];
            scr[wv * E + 32 + quad * 8 + j] = tk1[j];
        }
    }
    __syncthreads();

    // x = [tmp | target | other]
    if (t < 64)
        xS[t] = (scr[t] + scr[64 + t]) + (scr[128 + t] + scr[192 + t]);
    else if (t < 128)
        xS[t] = tgtS[t - 64];
    else
        xS[t] = oth;
    __syncthreads();

    // ---- Phase D: MLP head --------------------------------------------
    // h1: out[j] = relu(sum_c x[c]*oW1[c][j] + ob1[j]), 128 outs, 256 dot
    // thread (g = t&31, s = t>>5): outputs 4g..4g+3, c in [32s, 32s+32)
    {
        const int g = t & 31, s = t >> 5;
        const float* wbase = oW1 + 4 * g;
        const int c0 = s * 32;
        float ax = 0.f, ay = 0.f, az = 0.f, aw = 0.f;
        #pragma unroll 8
        for (int i = 0; i < 32; ++i) {
            const int c = c0 + i;
            float xv = xS[c];
            float4 w4 = *(const float4*)(wbase + (size_t)c * F1);
            ax += xv * w4.x; ay += xv * w4.y;
            az += xv * w4.z; aw += xv * w4.w;
        }
        // combine the two s-values living in this wave (lane ^ 32)
        ax += __shfl_xor(ax, 32);
        ay += __shfl_xor(ay, 32);
        az += __shfl_xor(az, 32);
        aw += __shfl_xor(aw, 32);
        if (lane < 32) {
            float4 r = { ax, ay, az, aw };
            *(float4*)&scr[wv * 128 + 4 * g] = r;
        }
    }
    __syncthreads();
    if (t < F1)
        h1S[t] = fmaxf((scr[t] + scr[128 + t]) + (scr[256 + t] + scr[384 + t]) + ob1[t], 0.f);
    __syncthreads();

    // h2: 85 outs, 128 dot, split 2 ways over c
    {
        const int o = t & 127, ph = t >> 7;
        if (o < F2) {
            float sA = 0.f, sB = 0.f;
            const int c0 = ph * 64;
            #pragma unroll 8
            for (int c = 0; c < 64; c += 2) {
                sA += h1S[c0 + c]     * oW2[(size_t)(c0 + c) * F2 + o];
                sB += h1S[c0 + c + 1] * oW2[(size_t)(c0 + c + 1) * F2 + o];
            }
            scr[ph * 128 + o] = sA + sB;
        }
    }
    __syncthreads();
    if (t < F2) h2S[t] = fmaxf(scr[t] + scr[128 + t] + ob2[t], 0.f);
    __syncthreads();

    // h3: 64 outs, 85 dot, split 4 ways over c (all 256 threads)
    {
        const int o = t & 63, ph = t >> 6;
        const int c0 = (85 * ph) >> 2, c1 = (85 * (ph + 1)) >> 2;
        float s = 0.f;
        for (int c = c0; c < c1; ++c)
            s += h2S[c] * oW3[(size_t)c * F3 + o];
        scr[ph * 64 + o] = s;
    }
    __syncthreads();

    if (t < 64) {
        float v = fmaxf((scr[t] + scr[64 + t]) + (scr[128 + t] + scr[192 + t]) + ob3[t], 0.f) * fW[t];
        v += __shfl_xor(v, 1);  v += __shfl_xor(v, 2);  v += __shfl_xor(v, 4);
        v += __shfl_xor(v, 8);  v += __shfl_xor(v, 16); v += __shfl_xor(v, 32);
        if (t == 0) out[b] = 1.f / (1.f + __expf(-(v + fb[0])));
    }
}

extern "C" void kernel_launch(void* const* d_in, const int* in_sizes, int n_in,
                              void* d_out, int out_size, void* d_ws, size_t ws_size,
                              hipStream_t stream) {
    const float* hist   = (const float*)d_in[0];
    const float* target = (const float*)d_in[1];
    const float* other  = (const float*)d_in[2];
    const float* aW1    = (const float*)d_in[3];
    const float* ab1    = (const float*)d_in[4];
    const float* aW2    = (const float*)d_in[5];
    const float* ab2    = (const float*)d_in[6];
    const float* oW1    = (const float*)d_in[7];
    const float* ob1    = (const float*)d_in[8];
    const float* oW2    = (const float*)d_in[9];
    const float* ob2    = (const float*)d_in[10];
    const float* oW3    = (const float*)d_in[11];
    const float* ob3    = (const float*)d_in[12];
    const float* fW     = (const float*)d_in[13];
    const float* fb     = (const float*)d_in[14];
    float* out = (float*)d_out;

    din_kernel<<<BATCH, 256, 0, stream>>>(hist, target, other,
                                          aW1, ab1, aW2, ab2,
                                          oW1, ob1, oW2, ob2, oW3, ob3,
                                          fW, fb, out);
}